// Round 11
// baseline (244.598 us; speedup 1.0000x reference)
//
#include <hip/hip_runtime.h>
#include <hip/hip_bf16.h>

#define B_ROWS 8192
#define D_DIM  2048
#define C_DIM  1000
#define C_PAD  1024

#define EPS32   1.1920928955078125e-07f
// GAMMA = 1/exp(100) ~ 3.7e-44. GAMMA*rex ~ 1e-40 << ulp(h3~6.9) ~ 4.8e-7,
// so loss == mean(h3) exactly in fp32. rex pipeline deleted (round 5).
// Round 13: gemm 128x64 single-buffer (4/CU). fuse_z frozen ~55 (5 variants).
// Round 14: explicit dbuf regressed — single-buffer confirmed.
// Round 15: rownorm deleted via row-sum linearity (rowsum = z.wsum + bsum,
// computed in fuse_z; normalize+clamp+log fused into gemm epilogue).
// Round 16: r15's prep.wsum was COLUMN-MAJOR strided (64 low-TLP blocks walking
// 8KB stride = ~45us, ate the rownorm win). Now: 8 row-major partial blocks
// (coalesced, reg-accum) + tiny wsum_fin reduce kernel. gemm epilogue: rowsum/
// target loads hoisted out of the store loop (ILP batch + rcp up front).

typedef __attribute__((ext_vector_type(8))) short short8;   // 8 bf16 = 4 VGPRs
typedef __attribute__((ext_vector_type(4))) float f32x4;    // MFMA accumulator

#define GLOAD_LDS16(gptr, lptr) \
  __builtin_amdgcn_global_load_lds((const __attribute__((address_space(1))) void*)(gptr), \
                                   (__attribute__((address_space(3))) void*)(lptr), 16, 0, 0)

__device__ inline unsigned short f2bf(float x) {
  union { __hip_bfloat16 b; unsigned short u; } cv;
  cv.b = __float2bfloat16(x);
  return cv.u;
}

__device__ inline float bf2f(unsigned short u) {
  union { unsigned int i; float f; } c;
  c.i = (unsigned int)u << 16;
  return c.f;
}

__device__ inline float wave_red(float v) {
#pragma unroll
  for (int off = 32; off > 0; off >>= 1) v += __shfl_down(v, off, 64);
  return v;
}

// ---- prep:
//   blocks [0,1024):     cast cls_w row bid -> bf16 (pad rows 1000..1023 = 0).
//   blocks [1024,1032):  partial[g][c] = sum over rows [g*125,(g+1)*125) of
//                        cls_w[r][c] — ROW-MAJOR coalesced, 8 reg accumulators.
//   block 1032:          bsum = sum(cls_b).
__global__ __launch_bounds__(256) void prep(const float* __restrict__ cls_w,
                                            __hip_bfloat16* __restrict__ clsw_bf,
                                            const float* __restrict__ cls_b,
                                            float* __restrict__ partial,
                                            float* __restrict__ bsum) {
  int bid = blockIdx.x, tid = threadIdx.x;
  if (bid < 1024) {
    int j = (bid * 256 + tid) * 8;   // elem idx in [1024][2048]; row == bid
    int row = j >> 11;
    int col = j & 2047;
    union { unsigned short u[8]; uint4 v; } pk;
    if (row < C_DIM) {
      const float* src = cls_w + (size_t)row * D_DIM + col;
#pragma unroll
      for (int i2 = 0; i2 < 8; ++i2) pk.u[i2] = f2bf(src[i2]);
    } else {
#pragma unroll
      for (int i2 = 0; i2 < 8; ++i2) pk.u[i2] = 0;
    }
    *(uint4*)((unsigned short*)clsw_bf + j) = pk.v;
  } else if (bid < 1032) {
    int g = bid - 1024;
    const float* base = cls_w + (size_t)g * 125 * D_DIM + tid * 8;
    float4 sA = {0.f, 0.f, 0.f, 0.f}, sB = {0.f, 0.f, 0.f, 0.f};
#pragma unroll 4
    for (int r = 0; r < 125; ++r) {
      float4 a = *(const float4*)(base + (size_t)r * D_DIM);
      float4 b = *(const float4*)(base + (size_t)r * D_DIM + 4);
      sA.x += a.x; sA.y += a.y; sA.z += a.z; sA.w += a.w;
      sB.x += b.x; sB.y += b.y; sB.z += b.z; sB.w += b.w;
    }
    float* dst = partial + (size_t)g * D_DIM + tid * 8;
    *(float4*)dst = sA;
    *(float4*)(dst + 4) = sB;
  } else {
    float s = 0.f;
    int i0 = tid * 4;
    if (i0 < C_DIM)                   // 250 threads x 4 = 1000
      s = cls_b[i0] + cls_b[i0 + 1] + cls_b[i0 + 2] + cls_b[i0 + 3];
    s = wave_red(s);
    __shared__ float sm[4];
    if ((tid & 63) == 0) sm[tid >> 6] = s;
    __syncthreads();
    if (tid == 0) bsum[0] = sm[0] + sm[1] + sm[2] + sm[3];
  }
}

// ---- wsum_fin: wsum[c] = sum_g partial[g][c].  8 blocks x 256 threads.
__global__ __launch_bounds__(256) void wsum_fin(const float* __restrict__ partial,
                                                float* __restrict__ wsum) {
  int c = blockIdx.x * 256 + threadIdx.x;
  float s = 0.f;
#pragma unroll
  for (int g = 0; g < 8; ++g) s += partial[(size_t)g * D_DIM + c];
  wsum[c] = s;
}

// ---- fuse_z: block b == z-row b. Pack z_bf = bf16(feature+eps) (16B store) and
// compute rowsum[b] = dot(bf16-rounded z, wsum) + bsum (block reduction).
__global__ __launch_bounds__(256) void fuse_z(const float4* __restrict__ f4,
                                              const float4* __restrict__ e4,
                                              uint4* __restrict__ z4,
                                              const float* __restrict__ wsum,
                                              const float* __restrict__ bsum,
                                              float* __restrict__ rowsum) {
  int bid = blockIdx.x, tid = threadIdx.x;
  int t = bid * 256 + tid;
  int i0 = t * 2;
  float4 f0 = f4[i0], f1 = f4[i0 + 1];
  float4 e0 = e4[i0], e1 = e4[i0 + 1];
  float4 w0 = *(const float4*)(wsum + tid * 8);
  float4 w1 = *(const float4*)(wsum + tid * 8 + 4);
  union { unsigned short u[8]; uint4 v; } pz;
  pz.u[0] = f2bf(f0.x + e0.x);
  pz.u[1] = f2bf(f0.y + e0.y);
  pz.u[2] = f2bf(f0.z + e0.z);
  pz.u[3] = f2bf(f0.w + e0.w);
  pz.u[4] = f2bf(f1.x + e1.x);
  pz.u[5] = f2bf(f1.y + e1.y);
  pz.u[6] = f2bf(f1.z + e1.z);
  pz.u[7] = f2bf(f1.w + e1.w);
  z4[t] = pz.v;

  float d = bf2f(pz.u[0]) * w0.x + bf2f(pz.u[1]) * w0.y +
            bf2f(pz.u[2]) * w0.z + bf2f(pz.u[3]) * w0.w +
            bf2f(pz.u[4]) * w1.x + bf2f(pz.u[5]) * w1.y +
            bf2f(pz.u[6]) * w1.z + bf2f(pz.u[7]) * w1.w;
  d = wave_red(d);
  __shared__ float sm[4];
  if ((tid & 63) == 0) sm[tid >> 6] = d;
  __syncthreads();
  if (tid == 0) rowsum[bid] = sm[0] + sm[1] + sm[2] + sm[3] + bsum[0];
}

// ---- gemm + fused epilogue: logits = log(clamp((z@W^T + b) / rowsum)).
// Round-13 proven single-buffer 128x64 tile (4 blocks/CU), BK=64, 4 waves 2x2,
// XOR-swizzle: 16B chunk (row, cc) at slot row*8 + (cc ^ (row&7)).
// Epilogue: rowsum/target loads hoisted (ILP batch + rcp), then pure store loop.
__global__ __launch_bounds__(256) void gemm_bt(const __hip_bfloat16* __restrict__ A,
                                               const __hip_bfloat16* __restrict__ Bt,
                                               const float* __restrict__ cls_b,
                                               const float* __restrict__ rowsum,
                                               const int* __restrict__ target,
                                               float* __restrict__ out,
                                               float* __restrict__ rowloss) {
  __shared__ __align__(16) __hip_bfloat16 sA[128 * 64];   // 16 KB
  __shared__ __align__(16) __hip_bfloat16 sB[64 * 64];    //  8 KB
  const int tid = threadIdx.x;
  const int m0 = blockIdx.x * 128;
  const int n0 = blockIdx.y * 64;
  const int w = tid >> 6, lane = tid & 63;
  const int wm = (w & 1) * 64, wn = (w >> 1) * 32;
  const int l15 = lane & 15, quad = lane >> 4;

  f32x4 acc[4][2] = {};

  for (int k0 = 0; k0 < D_DIM; k0 += 64) {
#pragma unroll
    for (int i = 0; i < 4; ++i) {
      int j = i * 256 + tid;          // A: 1024 chunks of 16B (128 rows x 8)
      int row = j >> 3;
      int cc = (j & 7) ^ (row & 7);   // inverse of the swizzle (XOR involution)
      GLOAD_LDS16(A + (size_t)(m0 + row) * D_DIM + k0 + cc * 8, &sA[j * 8]);
    }
#pragma unroll
    for (int i = 0; i < 2; ++i) {
      int j = i * 256 + tid;          // B: 512 chunks (64 rows x 8)
      int row = j >> 3;
      int cc = (j & 7) ^ (row & 7);
      GLOAD_LDS16(Bt + (size_t)(n0 + row) * D_DIM + k0 + cc * 8, &sB[j * 8]);
    }
    __syncthreads();
#pragma unroll
    for (int kk = 0; kk < 64; kk += 32) {
      const int ccr = (kk >> 3) + quad;   // which 8-elem chunk along K
      short8 af[4], bfr[2];
#pragma unroll
      for (int i = 0; i < 4; ++i) {
        int r = wm + i * 16 + l15;
        af[i] = *(const short8*)&sA[(r * 8 + (ccr ^ (r & 7))) * 8];
      }
#pragma unroll
      for (int jn = 0; jn < 2; ++jn) {
        int r = wn + jn * 16 + l15;
        bfr[jn] = *(const short8*)&sB[(r * 8 + (ccr ^ (r & 7))) * 8];
      }
#pragma unroll
      for (int i = 0; i < 4; ++i)
#pragma unroll
        for (int jn = 0; jn < 2; ++jn)
          acc[i][jn] = __builtin_amdgcn_mfma_f32_16x16x32_bf16(af[i], bfr[jn], acc[i][jn], 0, 0, 0);
    }
    __syncthreads();
  }

  // fused epilogue: C/D layout col=lane&15, row=quad*4+reg (m89-verified)
  float bias[2]; int bcol[2];
#pragma unroll
  for (int jn = 0; jn < 2; ++jn) {
    bcol[jn] = n0 + wn + jn * 16 + l15;
    bias[jn] = (bcol[jn] < C_DIM) ? cls_b[bcol[jn]] : 0.f;
  }
  // hoist per-row scalars: 16 rowsum + 16 target loads issued as one ILP batch
  const int rowb = m0 + wm + quad * 4;
  float rinv[16]; int tgt[16];
#pragma unroll
  for (int i = 0; i < 4; ++i)
#pragma unroll
    for (int r = 0; r < 4; ++r) {
      rinv[i * 4 + r] = rowsum[rowb + i * 16 + r];
      tgt[i * 4 + r]  = target[rowb + i * 16 + r];
    }
#pragma unroll
  for (int k = 0; k < 16; ++k) rinv[k] = 1.0f / rinv[k];

#pragma unroll
  for (int i = 0; i < 4; ++i) {
#pragma unroll
    for (int r = 0; r < 4; ++r) {
      int row = rowb + i * 16 + r;
      float inv = rinv[i * 4 + r];
      int tg = tgt[i * 4 + r];
      float* orow = out + (size_t)row * C_DIM;
#pragma unroll
      for (int jn = 0; jn < 2; ++jn) {
        int col = bcol[jn];
        if (col < C_DIM) {
          float p = (acc[i][jn][r] + bias[jn]) * inv;
          p = fminf(fmaxf(p, EPS32), 1.0f - EPS32);
          float lg = __logf(p);
          orow[col] = lg;
          if (col == tg) rowloss[row] = -lg;
        }
      }
    }
  }
}

// ---- finalize: loss = mean(rowloss). One 1024-thread block, ILP-8, plain store.
__global__ __launch_bounds__(1024) void finalize(const float* __restrict__ rowloss,
                                                 float* __restrict__ out_loss) {
  int tid = threadIdx.x;
  float a[8];
#pragma unroll
  for (int j = 0; j < 8; ++j) a[j] = rowloss[tid + j * 1024];
  float s = 0.f;
#pragma unroll
  for (int j = 0; j < 8; ++j) s += a[j];
  s = wave_red(s);
  __shared__ float sm[16];
  if ((tid & 63) == 0) sm[tid >> 6] = s;
  __syncthreads();
  if (tid == 0) {
    float t = 0.f;
#pragma unroll
    for (int k = 0; k < 16; ++k) t += sm[k];
    out_loss[0] = t * (1.0f / B_ROWS);
  }
}

extern "C" void kernel_launch(void* const* d_in, const int* in_sizes, int n_in,
                              void* d_out, int out_size, void* d_ws, size_t ws_size,
                              hipStream_t stream) {
  const float* feature = (const float*)d_in[0];
  const float* cls_w   = (const float*)d_in[3];
  const float* cls_b   = (const float*)d_in[4];
  const float* eps     = (const float*)d_in[5];
  const int*   target  = (const int*)d_in[6];
  float* out = (float*)d_out;
  float* out_loss = out + (size_t)B_ROWS * C_DIM;

  char* ws = (char*)d_ws;
  __hip_bfloat16* z_bf    = (__hip_bfloat16*)ws;                   // 33554432 B
  __hip_bfloat16* clsw_bf = (__hip_bfloat16*)(ws + 33554432);      //  4194304 B
  float*          rowloss = (float*)(ws + 37748736);               //    32768 B
  float*          rowsum  = (float*)(ws + 37781504);               //    32768 B
  float*          wsum    = (float*)(ws + 37814272);               //     8192 B
  float*          bsum    = (float*)(ws + 37822464);               //      256 B
  float*          partial = (float*)(ws + 37822720);               //    65536 B

  prep<<<dim3(1024 + 8 + 1), 256, 0, stream>>>(cls_w, clsw_bf, cls_b, partial, bsum);
  wsum_fin<<<dim3(8), 256, 0, stream>>>(partial, wsum);
  fuse_z<<<dim3(B_ROWS), 256, 0, stream>>>((const float4*)feature, (const float4*)eps,
                                           (uint4*)z_bf, wsum, bsum, rowsum);
  gemm_bt<<<dim3(B_ROWS / 128, C_PAD / 64), 256, 0, stream>>>(z_bf, clsw_bf, cls_b,
                                                              rowsum, target, out, rowloss);
  finalize<<<dim3(1), 1024, 0, stream>>>(rowloss, out_loss);
}

// Round 12
// 237.371 us; speedup vs baseline: 1.0304x; 1.0304x over previous
//
#include <hip/hip_runtime.h>
#include <hip/hip_bf16.h>

#define B_ROWS 8192
#define D_DIM  2048
#define C_DIM  1000
#define C_PAD  1024

#define EPS32   1.1920928955078125e-07f
// GAMMA = 1/exp(100) ~ 3.7e-44. GAMMA*rex ~ 1e-40 << ulp(h3~6.9) ~ 4.8e-7,
// so loss == mean(h3) exactly in fp32. rex pipeline deleted (round 5).
// Round 13: gemm 128x64 single-buffer (4/CU). fuse_z frozen ~55 (5 variants).
// Round 15: rownorm deleted via row-sum linearity (rowsum = z.wsum + bsum).
// Rounds 16/17 post-mortem: BOTH wsum implementations were block-starved
// (r10: 64 strided blocks ~45us; r11: 8 blocks = 8 CUs ~50us). Round 17:
// wsum = 125 coalesced blocks x 8 rows -> partial[125][2048] (64KB/block),
// wsum_fin reduces L2-resident 1MB. cls_w cast moved back into fuse_z's tail
// blocks (rode free there in r8); prep is now just wsum/bsum (~5us).

typedef __attribute__((ext_vector_type(8))) short short8;   // 8 bf16 = 4 VGPRs
typedef __attribute__((ext_vector_type(4))) float f32x4;    // MFMA accumulator

#define GLOAD_LDS16(gptr, lptr) \
  __builtin_amdgcn_global_load_lds((const __attribute__((address_space(1))) void*)(gptr), \
                                   (__attribute__((address_space(3))) void*)(lptr), 16, 0, 0)

__device__ inline unsigned short f2bf(float x) {
  union { __hip_bfloat16 b; unsigned short u; } cv;
  cv.b = __float2bfloat16(x);
  return cv.u;
}

__device__ inline float bf2f(unsigned short u) {
  union { unsigned int i; float f; } c;
  c.i = (unsigned int)u << 16;
  return c.f;
}

__device__ inline float wave_red(float v) {
#pragma unroll
  for (int off = 32; off > 0; off >>= 1) v += __shfl_down(v, off, 64);
  return v;
}

// ---- prep: blocks [0,125): partial[g][c] = sum of cls_w rows [8g, 8g+8) —
//            coalesced (256 thr x 8 cols, 2 float4/row), 64KB/block.
//            block 125: bsum = sum(cls_b).
__global__ __launch_bounds__(256) void prep(const float* __restrict__ cls_w,
                                            const float* __restrict__ cls_b,
                                            float* __restrict__ partial,
                                            float* __restrict__ bsum) {
  int bid = blockIdx.x, tid = threadIdx.x;
  if (bid < 125) {
    const float* base = cls_w + (size_t)bid * 8 * D_DIM + tid * 8;
    float4 sA = {0.f, 0.f, 0.f, 0.f}, sB = {0.f, 0.f, 0.f, 0.f};
#pragma unroll
    for (int r = 0; r < 8; ++r) {
      float4 a = *(const float4*)(base + (size_t)r * D_DIM);
      float4 b = *(const float4*)(base + (size_t)r * D_DIM + 4);
      sA.x += a.x; sA.y += a.y; sA.z += a.z; sA.w += a.w;
      sB.x += b.x; sB.y += b.y; sB.z += b.z; sB.w += b.w;
    }
    float* dst = partial + (size_t)bid * D_DIM + tid * 8;
    *(float4*)dst = sA;
    *(float4*)(dst + 4) = sB;
  } else {
    float s = 0.f;
    int i0 = tid * 4;
    if (i0 < C_DIM)                   // 250 threads x 4 = 1000
      s = cls_b[i0] + cls_b[i0 + 1] + cls_b[i0 + 2] + cls_b[i0 + 3];
    s = wave_red(s);
    __shared__ float sm[4];
    if ((tid & 63) == 0) sm[tid >> 6] = s;
    __syncthreads();
    if (tid == 0) bsum[0] = sm[0] + sm[1] + sm[2] + sm[3];
  }
}

// ---- wsum_fin: wsum[c] = sum_{g<125} partial[g][c]. 1MB L2-resident input.
__global__ __launch_bounds__(256) void wsum_fin(const float* __restrict__ partial,
                                                float* __restrict__ wsum) {
  int c = blockIdx.x * 256 + threadIdx.x;
  float s = 0.f;
  for (int g = 0; g < 125; ++g) s += partial[(size_t)g * D_DIM + c];
  wsum[c] = s;
}

// ---- fuse_z:
//   blocks [0,8192):      block b == z-row b: pack z_bf = bf16(feature+eps)
//                         (16B store) and rowsum[b] = dot(bf16 z, wsum) + bsum.
//   blocks [8192,9216):   cast cls_w -> bf16 padded [1024][2048] (tail, as r8).
__global__ __launch_bounds__(256) void fuse_z(const float4* __restrict__ f4,
                                              const float4* __restrict__ e4,
                                              uint4* __restrict__ z4,
                                              const float* __restrict__ cls_w,
                                              __hip_bfloat16* __restrict__ clsw_bf,
                                              const float* __restrict__ wsum,
                                              const float* __restrict__ bsum,
                                              float* __restrict__ rowsum) {
  int bid = blockIdx.x, tid = threadIdx.x;
  if (bid < B_ROWS) {
    int t = bid * 256 + tid;
    int i0 = t * 2;
    float4 f0 = f4[i0], f1 = f4[i0 + 1];
    float4 e0 = e4[i0], e1 = e4[i0 + 1];
    float4 w0 = *(const float4*)(wsum + tid * 8);
    float4 w1 = *(const float4*)(wsum + tid * 8 + 4);
    union { unsigned short u[8]; uint4 v; } pz;
    pz.u[0] = f2bf(f0.x + e0.x);
    pz.u[1] = f2bf(f0.y + e0.y);
    pz.u[2] = f2bf(f0.z + e0.z);
    pz.u[3] = f2bf(f0.w + e0.w);
    pz.u[4] = f2bf(f1.x + e1.x);
    pz.u[5] = f2bf(f1.y + e1.y);
    pz.u[6] = f2bf(f1.z + e1.z);
    pz.u[7] = f2bf(f1.w + e1.w);
    z4[t] = pz.v;

    float d = bf2f(pz.u[0]) * w0.x + bf2f(pz.u[1]) * w0.y +
              bf2f(pz.u[2]) * w0.z + bf2f(pz.u[3]) * w0.w +
              bf2f(pz.u[4]) * w1.x + bf2f(pz.u[5]) * w1.y +
              bf2f(pz.u[6]) * w1.z + bf2f(pz.u[7]) * w1.w;
    d = wave_red(d);
    __shared__ float sm[4];
    if ((tid & 63) == 0) sm[tid >> 6] = d;
    __syncthreads();
    if (tid == 0) rowsum[bid] = sm[0] + sm[1] + sm[2] + sm[3] + bsum[0];
  } else {
    int j = ((bid - B_ROWS) * 256 + tid) * 8;   // elem idx in [1024][2048]
    int row = j >> 11;
    int col = j & 2047;
    union { unsigned short u[8]; uint4 v; } pk;
    if (row < C_DIM) {
      const float* src = cls_w + (size_t)row * D_DIM + col;
#pragma unroll
      for (int i2 = 0; i2 < 8; ++i2) pk.u[i2] = f2bf(src[i2]);
    } else {
#pragma unroll
      for (int i2 = 0; i2 < 8; ++i2) pk.u[i2] = 0;
    }
    *(uint4*)((unsigned short*)clsw_bf + j) = pk.v;
  }
}

// ---- gemm + fused epilogue: logits = log(clamp((z@W^T + b) / rowsum)).
// Round-13 proven single-buffer 128x64 tile (4 blocks/CU), BK=64, 4 waves 2x2,
// XOR-swizzle: 16B chunk (row, cc) at slot row*8 + (cc ^ (row&7)).
// Epilogue: rowsum/target hoisted (ILP batch + rcp), then pure store loop.
__global__ __launch_bounds__(256) void gemm_bt(const __hip_bfloat16* __restrict__ A,
                                               const __hip_bfloat16* __restrict__ Bt,
                                               const float* __restrict__ cls_b,
                                               const float* __restrict__ rowsum,
                                               const int* __restrict__ target,
                                               float* __restrict__ out,
                                               float* __restrict__ rowloss) {
  __shared__ __align__(16) __hip_bfloat16 sA[128 * 64];   // 16 KB
  __shared__ __align__(16) __hip_bfloat16 sB[64 * 64];    //  8 KB
  const int tid = threadIdx.x;
  const int m0 = blockIdx.x * 128;
  const int n0 = blockIdx.y * 64;
  const int w = tid >> 6, lane = tid & 63;
  const int wm = (w & 1) * 64, wn = (w >> 1) * 32;
  const int l15 = lane & 15, quad = lane >> 4;

  f32x4 acc[4][2] = {};

  for (int k0 = 0; k0 < D_DIM; k0 += 64) {
#pragma unroll
    for (int i = 0; i < 4; ++i) {
      int j = i * 256 + tid;          // A: 1024 chunks of 16B (128 rows x 8)
      int row = j >> 3;
      int cc = (j & 7) ^ (row & 7);   // inverse of the swizzle (XOR involution)
      GLOAD_LDS16(A + (size_t)(m0 + row) * D_DIM + k0 + cc * 8, &sA[j * 8]);
    }
#pragma unroll
    for (int i = 0; i < 2; ++i) {
      int j = i * 256 + tid;          // B: 512 chunks (64 rows x 8)
      int row = j >> 3;
      int cc = (j & 7) ^ (row & 7);
      GLOAD_LDS16(Bt + (size_t)(n0 + row) * D_DIM + k0 + cc * 8, &sB[j * 8]);
    }
    __syncthreads();
#pragma unroll
    for (int kk = 0; kk < 64; kk += 32) {
      const int ccr = (kk >> 3) + quad;   // which 8-elem chunk along K
      short8 af[4], bfr[2];
#pragma unroll
      for (int i = 0; i < 4; ++i) {
        int r = wm + i * 16 + l15;
        af[i] = *(const short8*)&sA[(r * 8 + (ccr ^ (r & 7))) * 8];
      }
#pragma unroll
      for (int jn = 0; jn < 2; ++jn) {
        int r = wn + jn * 16 + l15;
        bfr[jn] = *(const short8*)&sB[(r * 8 + (ccr ^ (r & 7))) * 8];
      }
#pragma unroll
      for (int i = 0; i < 4; ++i)
#pragma unroll
        for (int jn = 0; jn < 2; ++jn)
          acc[i][jn] = __builtin_amdgcn_mfma_f32_16x16x32_bf16(af[i], bfr[jn], acc[i][jn], 0, 0, 0);
    }
    __syncthreads();
  }

  // fused epilogue: C/D layout col=lane&15, row=quad*4+reg (m89-verified)
  float bias[2]; int bcol[2];
#pragma unroll
  for (int jn = 0; jn < 2; ++jn) {
    bcol[jn] = n0 + wn + jn * 16 + l15;
    bias[jn] = (bcol[jn] < C_DIM) ? cls_b[bcol[jn]] : 0.f;
  }
  const int rowb = m0 + wm + quad * 4;
  float rinv[16]; int tgt[16];
#pragma unroll
  for (int i = 0; i < 4; ++i)
#pragma unroll
    for (int r = 0; r < 4; ++r) {
      rinv[i * 4 + r] = rowsum[rowb + i * 16 + r];
      tgt[i * 4 + r]  = target[rowb + i * 16 + r];
    }
#pragma unroll
  for (int k = 0; k < 16; ++k) rinv[k] = 1.0f / rinv[k];

#pragma unroll
  for (int i = 0; i < 4; ++i) {
#pragma unroll
    for (int r = 0; r < 4; ++r) {
      int row = rowb + i * 16 + r;
      float inv = rinv[i * 4 + r];
      int tg = tgt[i * 4 + r];
      float* orow = out + (size_t)row * C_DIM;
#pragma unroll
      for (int jn = 0; jn < 2; ++jn) {
        int col = bcol[jn];
        if (col < C_DIM) {
          float p = (acc[i][jn][r] + bias[jn]) * inv;
          p = fminf(fmaxf(p, EPS32), 1.0f - EPS32);
          float lg = __logf(p);
          orow[col] = lg;
          if (col == tg) rowloss[row] = -lg;
        }
      }
    }
  }
}

// ---- finalize: loss = mean(rowloss). One 1024-thread block, ILP-8, plain store.
__global__ __launch_bounds__(1024) void finalize(const float* __restrict__ rowloss,
                                                 float* __restrict__ out_loss) {
  int tid = threadIdx.x;
  float a[8];
#pragma unroll
  for (int j = 0; j < 8; ++j) a[j] = rowloss[tid + j * 1024];
  float s = 0.f;
#pragma unroll
  for (int j = 0; j < 8; ++j) s += a[j];
  s = wave_red(s);
  __shared__ float sm[16];
  if ((tid & 63) == 0) sm[tid >> 6] = s;
  __syncthreads();
  if (tid == 0) {
    float t = 0.f;
#pragma unroll
    for (int k = 0; k < 16; ++k) t += sm[k];
    out_loss[0] = t * (1.0f / B_ROWS);
  }
}

extern "C" void kernel_launch(void* const* d_in, const int* in_sizes, int n_in,
                              void* d_out, int out_size, void* d_ws, size_t ws_size,
                              hipStream_t stream) {
  const float* feature = (const float*)d_in[0];
  const float* cls_w   = (const float*)d_in[3];
  const float* cls_b   = (const float*)d_in[4];
  const float* eps     = (const float*)d_in[5];
  const int*   target  = (const int*)d_in[6];
  float* out = (float*)d_out;
  float* out_loss = out + (size_t)B_ROWS * C_DIM;

  char* ws = (char*)d_ws;
  __hip_bfloat16* z_bf    = (__hip_bfloat16*)ws;                   // 33554432 B
  __hip_bfloat16* clsw_bf = (__hip_bfloat16*)(ws + 33554432);      //  4194304 B
  float*          rowloss = (float*)(ws + 37748736);               //    32768 B
  float*          rowsum  = (float*)(ws + 37781504);               //    32768 B
  float*          wsum    = (float*)(ws + 37814272);               //     8192 B
  float*          bsum    = (float*)(ws + 37822464);               //      256 B
  float*          partial = (float*)(ws + 37822720);               //  1024000 B

  prep<<<dim3(125 + 1), 256, 0, stream>>>(cls_w, cls_b, partial, bsum);
  wsum_fin<<<dim3(8), 256, 0, stream>>>(partial, wsum);
  fuse_z<<<dim3(B_ROWS + 1024), 256, 0, stream>>>((const float4*)feature,
                                                  (const float4*)eps, (uint4*)z_bf,
                                                  cls_w, clsw_bf, wsum, bsum, rowsum);
  gemm_bt<<<dim3(B_ROWS / 128, C_PAD / 64), 256, 0, stream>>>(z_bf, clsw_bf, cls_b,
                                                              rowsum, target, out, rowloss);
  finalize<<<dim3(1), 1024, 0, stream>>>(rowloss, out_loss);
}